// Round 8
// baseline (3137.542 us; speedup 1.0000x reference)
//
#include <hip/hip_runtime.h>

#define TSTEPS 784
#define BATCH  128
#define HID    256
#define WPG    8     // workgroups per group
#define BG     4     // batches per group
#define NGRP   (BATCH / BG)          // 32 groups
#define COLS   32    // hidden cols owned per WG
#define RLOC   128   // local gate rows per WG (32 cols x 4 gates, interleaved)
typedef unsigned long long u64;
typedef float v4f __attribute__((ext_vector_type(4)));
typedef float v2f __attribute__((ext_vector_type(2)));

// ---------------- prep: permute input (x transposed to [b][t]) ----------------
__global__ void prep_x(const float* __restrict__ in, const int* __restrict__ perm,
                       float* __restrict__ xp) {
    int b = blockIdx.x;
    for (int t = threadIdx.x; t < TSTEPS; t += blockDim.x)
        xp[b * TSTEPS + t] = in[b * TSTEPS + perm[t]];
}

// slots[parity][b][k]: hi32 = tag, lo32 = f32 bits. parity0: tag0/val0 = 0ull.
__global__ void prep_slots(u64* __restrict__ slots) {
    int i = blockIdx.x * blockDim.x + threadIdx.x;
    if (i < BATCH * HID)          slots[i] = 0ull;
    else if (i < 2 * BATCH * HID) slots[i] = 0xFFFFFFFF00000000ull;
}

// packed 2-wide f32 fma: acc += a*b (element-wise on reg pairs)
#define PK_FMA(acc, a, b) \
    asm("v_pk_fma_f32 %0, %1, %2, %0" : "+v"(acc) : "v"(a), "v"(b))

// ---------------- main persistent LSTM kernel ----------------
// grid 256 x 1024. group g = blockIdx&31 owns batches [4g,4g+4).
// WG wgi = blockIdx>>5 owns cols [32wgi, 32wgi+32).
// thread: r = tid>>3 in [0,128) with col = r>>2, gate = r&3 (gates of one col
// sit 8 lanes apart -> in-wave epilogue via shfl_down). s = tid&7 k-slice of
// 32. 32 weights/thread in VGPRs (pinned), rotate-stored -> conflict-free
// broadcast ds_read_b128. Dot uses v_pk_fma_f32 (2 MAC/instr).
__global__ __launch_bounds__(1024, 4) void lstm_kernel(
    const float* __restrict__ Whh, const float* __restrict__ Wih,
    const float* __restrict__ bih, const float* __restrict__ bhh,
    const float* __restrict__ xp, u64* __restrict__ slots)
{
    __shared__ float h_lds[BG * HID];            // 4 KB staged h_t  [b][k]
    __shared__ float x_lds[BG * TSTEPS];         // 12.25 KB
    __shared__ float c_lds[BG * COLS];           // [col*4 + b]
    __shared__ float bias_lds[RLOC];
    __shared__ float win_lds[RLOC];

    const int tid = threadIdx.x;
    const int g       = blockIdx.x & 31;
    const int wgi     = blockIdx.x >> 5;
    const int B0      = g * BG;
    const int colbase = wgi * COLS;

    const int r    = tid >> 3;               // local row 0..127
    const int s    = tid & 7;                // k-slice
    const int lane = tid & 63;
    const int col  = r >> 2;                 // local col 0..31
    const int gate = r & 3;                  // gate id (i,f,g,o)
    const int R = gate * 256 + colbase + col;  // global gate row

    // ---- one-time loads; rotate-store: reg d holds quad index (d+s)&7 ----
    v4f w0, w1, w2, w3, w4, w5, w6, w7;
    {
        const v4f* wp = (const v4f*)(Whh + R * HID + s * 32);
        w0 = wp[(0 + s) & 7]; w1 = wp[(1 + s) & 7];
        w2 = wp[(2 + s) & 7]; w3 = wp[(3 + s) & 7];
        w4 = wp[(4 + s) & 7]; w5 = wp[(5 + s) & 7];
        w6 = wp[(6 + s) & 7]; w7 = wp[(7 + s) & 7];
    }
    #define KEEPV(V) asm volatile("" : "+v"(V))
    KEEPV(w0); KEEPV(w1); KEEPV(w2); KEEPV(w3);
    KEEPV(w4); KEEPV(w5); KEEPV(w6); KEEPV(w7);
    #undef KEEPV

    if (tid < RLOC) {
        // bias/win indexed by local row r with the NEW (col,gate) mapping
        int gr = (tid & 3) * 256 + colbase + (tid >> 2);
        bias_lds[tid] = bih[gr] + bhh[gr];
        win_lds[tid]  = Wih[gr];
    }
    #pragma unroll
    for (int b = 0; b < BG; ++b)
        if (tid < TSTEPS) x_lds[b * TSTEPS + tid] = xp[(B0 + b) * TSTEPS + tid];
    if (tid < BG * COLS) c_lds[tid] = 0.f;
    __syncthreads();

    // poll target for this thread: element (pb, pk) of the group's h
    const int pb = tid >> 8, pk = tid & 255;
    u64* const slot0 = slots + (B0 + pb) * HID + pk;               // parity 0
    u64* const slot1 = slots + BATCH * HID + (B0 + pb) * HID + pk; // parity 1

    const bool is_upd = ((lane >> 3) & 3) == 0 && s < BG;  // updater lanes

    for (int t = 0; t < TSTEPS; ++t) {
        // ---- stage h_t: 2-deep pipelined poll of the tagged value ----
        {
            u64* sp = (t & 1) ? slot1 : slot0;
            u64 p0 = __hip_atomic_load(sp, __ATOMIC_RELAXED, __HIP_MEMORY_SCOPE_AGENT);
            u64 p1 = __hip_atomic_load(sp, __ATOMIC_RELAXED, __HIP_MEMORY_SCOPE_AGENT);
            while ((unsigned)(p0 >> 32) != (unsigned)t) {
                p0 = p1;
                p1 = __hip_atomic_load(sp, __ATOMIC_RELAXED, __HIP_MEMORY_SCOPE_AGENT);
            }
            h_lds[tid] = __uint_as_float((unsigned)p0);
        }
        __syncthreads();

        // ---- dot: pk_fma, weights in VGPRs, rotated broadcast b128 h reads ----
        v2f acc0 = {0.f, 0.f}, acc1 = {0.f, 0.f}, acc2 = {0.f, 0.f}, acc3 = {0.f, 0.f};
        const float* hbase = h_lds + s * 32;
        #define DOT_STEP(d, wd)                                               \
        {                                                                     \
            int off = (((d) + s) & 7) * 4;                                    \
            v4f hq0 = *(const v4f*)(hbase + off);                             \
            v4f hq1 = *(const v4f*)(hbase + 256 + off);                       \
            v4f hq2 = *(const v4f*)(hbase + 512 + off);                       \
            v4f hq3 = *(const v4f*)(hbase + 768 + off);                       \
            v2f wlo = __builtin_shufflevector(wd, wd, 0, 1);                  \
            v2f whi = __builtin_shufflevector(wd, wd, 2, 3);                  \
            v2f hl, hh;                                                       \
            hl = __builtin_shufflevector(hq0, hq0, 0, 1);                     \
            hh = __builtin_shufflevector(hq0, hq0, 2, 3);                     \
            PK_FMA(acc0, wlo, hl); PK_FMA(acc0, whi, hh);                     \
            hl = __builtin_shufflevector(hq1, hq1, 0, 1);                     \
            hh = __builtin_shufflevector(hq1, hq1, 2, 3);                     \
            PK_FMA(acc1, wlo, hl); PK_FMA(acc1, whi, hh);                     \
            hl = __builtin_shufflevector(hq2, hq2, 0, 1);                     \
            hh = __builtin_shufflevector(hq2, hq2, 2, 3);                     \
            PK_FMA(acc2, wlo, hl); PK_FMA(acc2, whi, hh);                     \
            hl = __builtin_shufflevector(hq3, hq3, 0, 1);                     \
            hh = __builtin_shufflevector(hq3, hq3, 2, 3);                     \
            PK_FMA(acc3, wlo, hl); PK_FMA(acc3, whi, hh);                     \
        }
        DOT_STEP(0, w0) DOT_STEP(1, w1) DOT_STEP(2, w2) DOT_STEP(3, w3)
        DOT_STEP(4, w4) DOT_STEP(5, w5) DOT_STEP(6, w6) DOT_STEP(7, w7)
        #undef DOT_STEP

        float a0 = acc0.x + acc0.y;
        float a1 = acc1.x + acc1.y;
        float a2 = acc2.x + acc2.y;
        float a3 = acc3.x + acc3.y;

        // ---- k-reduce across the 8 slice-lanes (in-wave butterfly) ----
        #pragma unroll
        for (int m = 1; m < 8; m <<= 1) {
            a0 += __shfl_xor(a0, m, 64);
            a1 += __shfl_xor(a1, m, 64);
            a2 += __shfl_xor(a2, m, 64);
            a3 += __shfl_xor(a3, m, 64);
        }

        // ---- act at lanes s<4 (batch b=s), predicated sigmoid/tanh ----
        float sum = (s == 0) ? a0 : (s == 1) ? a1 : (s == 2) ? a2 : a3;
        float xv  = x_lds[s * TSTEPS + t];          // valid for s<4
        float full = fmaf(win_lds[r], xv, sum + bias_lds[r]);
        // tanh(x) = 2*sigmoid(2x)-1; unified: act = A/(1+e^-pre) - B
        float pre = (gate == 2) ? 2.f * full : full;
        float e   = __expf(-pre);
        float rec = 1.f / (1.f + e);
        float act = (gate == 2) ? fmaf(2.f, rec, -1.f) : rec;

        // ---- in-wave gather of i,f,g,o (gates sit 8 lanes apart) ----
        float act_f = __shfl_down(act, 8, 64);
        float act_g = __shfl_down(act, 16, 64);
        float act_o = __shfl_down(act, 24, 64);

        if (is_upd) {   // lanes with gate==0 octets, s<4: own (col, b=s)
            int b = s;
            int ci = col * 4 + b;
            float cn = fmaf(act_f, c_lds[ci], act * act_g);
            float tc = 2.f / (1.f + __expf(-2.f * cn)) - 1.f;
            float hn = act_o * tc;
            u64 val = ((u64)(unsigned)(t + 1) << 32) | (u64)__float_as_uint(hn);
            u64* dp = slots + ((t + 1) & 1) * (BATCH * HID)
                            + (B0 + b) * HID + colbase + col;
            __hip_atomic_store(dp, val, __ATOMIC_RELAXED, __HIP_MEMORY_SCOPE_AGENT);
            c_lds[ci] = cn;
        }
        // barrier: all h_lds reads for step t are done before next staging
        __syncthreads();
    }
}

// ---------------- final linear: out = h_784 @ lin_W.T + lin_b ----------------
__global__ void out_kernel(const u64* __restrict__ slots, const float* __restrict__ linW,
                           const float* __restrict__ linb, float* __restrict__ out) {
    __shared__ float hl[HID];
    int b = blockIdx.x;
    // T=784 even -> final h is in parity-0 slots, low 32 bits
    for (int k = threadIdx.x; k < HID; k += blockDim.x)
        hl[k] = __uint_as_float((unsigned)slots[b * HID + k]);
    __syncthreads();
    if (threadIdx.x < 10) {
        int n = threadIdx.x;
        float acc = linb[n];
        for (int k = 0; k < HID; ++k) acc = fmaf(hl[k], linW[n * HID + k], acc);
        out[b * 10 + n] = acc;
    }
}

extern "C" void kernel_launch(void* const* d_in, const int* in_sizes, int n_in,
                              void* d_out, int out_size, void* d_ws, size_t ws_size,
                              hipStream_t stream) {
    const float* inputs = (const float*)d_in[0];
    const int*   perm   = (const int*)d_in[1];
    const float* Wih    = (const float*)d_in[2];
    const float* Whh    = (const float*)d_in[3];
    const float* bih    = (const float*)d_in[4];
    const float* bhh    = (const float*)d_in[5];
    const float* linW   = (const float*)d_in[6];
    const float* linb   = (const float*)d_in[7];
    float* out = (float*)d_out;

    // d_ws layout: slots[2][128][256] u64 (512KB) | xp[128][784] f32 (401KB)
    u64*   slots = (u64*)d_ws;
    float* xp    = (float*)(slots + 2 * BATCH * HID);

    prep_x<<<BATCH, 256, 0, stream>>>(inputs, perm, xp);
    prep_slots<<<(2 * BATCH * HID + 255) / 256, 256, 0, stream>>>(slots);
    lstm_kernel<<<NGRP * WPG, 1024, 0, stream>>>(Whh, Wih, bih, bhh, xp, slots);
    out_kernel<<<BATCH, 64, 0, stream>>>(slots, linW, linb, out);
}